// Round 6
// baseline (405.771 us; speedup 1.0000x reference)
//
#include <hip/hip_runtime.h>

#define NB 512
#define NT 512
#define NL 64
#define L2E 1.4426950408889634f   // log2(e)
#define LN2 0.6931471805599453f   // ln(2)

__global__ void zero_out_kernel(float* out) { *out = 0.0f; }

// R6: TWO interleaved batches per wave (b, b+256), grid 256. The R5 kernel
// was a latency-bound serial scan (773 cyc/step; VALU 23.6%, LDS ~25%): one
// dependence chain per wave left the LDS write->read latency unfilled.
// Chain B's FMAs fill chain A's stalls. ecol (exp2-domain trans column) is
// shared; q/FIFO/C/accumulators duplicated. Still call-free (R5 lesson:
// OCML calls pin live values into spill slots).
__global__
__attribute__((amdgpu_flat_work_group_size(64, 64), amdgpu_waves_per_eu(1, 1)))
void crf_nll_kernel(
    const float* __restrict__ emission,     // B,T,L
    const int*   __restrict__ target,       // B,T
    const float* __restrict__ mask,         // B,T
    const float* __restrict__ start_trans,  // L
    const float* __restrict__ trans,        // L,L
    const float* __restrict__ end_trans,    // L
    float* __restrict__ out)
{
  const int j = threadIdx.x;  // 0..63
  const int bA = blockIdx.x;          // 0..255
  const int bB = bA + NB / 2;         // 256..511

  const float* emA = emission + (size_t)bA * NT * NL;
  const float* emB = emission + (size_t)bB * NT * NL;
  const float* mkA = mask + (size_t)bA * NT;
  const float* mkB = mask + (size_t)bB * NT;

  // ---------------- path scores (parallel over t, then wave-reduce) ---------
  float psv[2] = {0.0f, 0.0f};
  #pragma unroll
  for (int p = 0; p < 2; ++p) {
    const int b = p ? bB : bA;
    const float* em_b = p ? emB : emA;
    const float* mk_b = p ? mkB : mkA;
    const int* tg_b = target + (size_t)b * NT;
    float ps = 0.0f;
    #pragma unroll
    for (int c = 0; c < NT / 64; ++c) {
      int t = c * 64 + j;
      int cur = tg_b[t];
      float m  = mk_b[t];
      float mn = (t + 1 < NT) ? mk_b[t + 1] : 0.0f;
      if (t == 0) {
        ps += start_trans[cur] + em_b[cur];
      } else {
        int prev = tg_b[t - 1];
        if (m > 0.5f)
          ps += trans[prev * NL + cur] + em_b[(size_t)t * NL + cur];
        if (m - mn > 0.5f)                 // end_mask = m_t & !m_{t+1}
          ps += end_trans[cur];
      }
    }
    #pragma unroll
    for (int off = 32; off; off >>= 1) ps += __shfl_down(ps, off, 64);
    psv[p] = ps;                           // valid in lane 0
  }

  // -------- exp2-domain trans column (shared by both chains) ----------------
  float ecol[NL];
  #pragma unroll
  for (int i = 0; i < NL; ++i)
    ecol[i] = __builtin_amdgcn_exp2f(L2E * trans[i * NL + j]);  // coalesced
  const float endt = __builtin_amdgcn_exp2f(L2E * end_trans[j]);

  __shared__ __align__(16) float qbufA[NL];
  __shared__ __align__(16) float qbufB[NL];
  const float4* qvA = (const float4*)qbufA;
  const float4* qvB = (const float4*)qbufB;

  float CA = 0.0f, CB = 0.0f;                  // log2-scale accumulators
  float qa = __builtin_amdgcn_exp2f(L2E * (start_trans[j] + emA[j]));
  float qb = __builtin_amdgcn_exp2f(L2E * (start_trans[j] + emB[j]));

  // 8-deep emission FIFOs, pre-scaled by log2(e)
  float pfA[8], pfB[8];
  #pragma unroll
  for (int u = 0; u < 8; ++u) {
    pfA[u] = L2E * emA[(size_t)u * NL + j];
    pfB[u] = L2E * emB[(size_t)u * NL + j];
  }

  #pragma unroll 1
  for (int c = 0; c < 8; ++c) {
    const int tb = c * 64;
    // per-chunk masks as wave-uniform 64-bit ballot words (both chains)
    int nidx = tb + j + 1;
    float mlA = mkA[tb + j];
    float mnA = (nidx < NT) ? mkA[nidx] : 0.0f;
    float mlB = mkB[tb + j];
    float mnB = (nidx < NT) ? mkB[nidx] : 0.0f;
    unsigned long long mbitsA = __ballot(mlA > 0.5f);
    unsigned long long ebitsA = __ballot(mlA - mnA > 0.5f);
    unsigned long long mbitsB = __ballot(mlB > 0.5f);
    unsigned long long ebitsB = __ballot(mlB - mnB > 0.5f);
    if (c == 0) { mbitsA &= ~1ull; ebitsA &= ~1ull;
                  mbitsB &= ~1ull; ebitsB &= ~1ull; }  // t=0 done by init

    #pragma unroll 1
    for (int i8 = 0; i8 < 64; i8 += 8) {
      #pragma unroll
      for (int u = 0; u < 8; ++u) {
        const int i = i8 + u;
        // write both states first; off-chain work fills write->read latency
        qbufA[j] = qa;
        qbufB[j] = qb;
        float eemA = __builtin_amdgcn_exp2f(pfA[u]);
        float eemB = __builtin_amdgcn_exp2f(pfB[u]);
        int tp = tb + i + 8; if (tp > NT - 1) tp = NT - 1;
        pfA[u] = L2E * emA[(size_t)tp * NL + j];       // prefetch t+8
        pfB[u] = L2E * emB[(size_t)tp * NL + j];
        float a0 = 0.f, a1 = 0.f, a2 = 0.f, a3 = 0.f;
        float b0 = 0.f, b1 = 0.f, b2 = 0.f, b3 = 0.f;
        #pragma unroll
        for (int k = 0; k < 16; ++k) {                 // interleave A/B reads
          float4 xa = qvA[k];
          a0 = fmaf(xa.x, ecol[4 * k + 0], a0);
          a1 = fmaf(xa.y, ecol[4 * k + 1], a1);
          a2 = fmaf(xa.z, ecol[4 * k + 2], a2);
          a3 = fmaf(xa.w, ecol[4 * k + 3], a3);
          float4 xb = qvB[k];
          b0 = fmaf(xb.x, ecol[4 * k + 0], b0);
          b1 = fmaf(xb.y, ecol[4 * k + 1], b1);
          b2 = fmaf(xb.z, ecol[4 * k + 2], b2);
          b3 = fmaf(xb.w, ecol[4 * k + 3], b3);
        }
        float smA = ((a0 + a1) + (a2 + a3)) * eemA;
        float smB = ((b0 + b1) + (b2 + b3)) * eemB;
        qa = ((mbitsA >> i) & 1) ? smA : qa;
        qa = ((ebitsA >> i) & 1) ? qa * endt : qa;
        qb = ((mbitsB >> i) & 1) ? smB : qb;
        qb = ((ebitsB >> i) & 1) ? qb * endt : qb;
        if ((u & 3) == 3) {                            // rescale every 4 steps
          float rA = __uint_as_float(
              __builtin_amdgcn_readfirstlane(__float_as_uint(qa)));
          float rB = __uint_as_float(
              __builtin_amdgcn_readfirstlane(__float_as_uint(qb)));
          qa *= __builtin_amdgcn_rcpf(rA);
          qb *= __builtin_amdgcn_rcpf(rB);
          CA += __builtin_amdgcn_logf(rA);             // log2
          CB += __builtin_amdgcn_logf(rB);
        }
      }
    }
  }

  // ---------------- normalizers + output ------------------------------------
  float sA = qa, sB = qb;
  #pragma unroll
  for (int off = 32; off; off >>= 1) {
    sA += __shfl_xor(sA, off, 64);
    sB += __shfl_xor(sB, off, 64);
  }
  if (j == 0) {
    float normA = (__builtin_amdgcn_logf(sA) + CA) * LN2;
    float normB = (__builtin_amdgcn_logf(sB) + CB) * LN2;
    atomicAdd(out, ((normA - psv[0]) + (normB - psv[1])) * (1.0f / (float)NB));
  }
}

extern "C" void kernel_launch(void* const* d_in, const int* in_sizes, int n_in,
                              void* d_out, int out_size, void* d_ws, size_t ws_size,
                              hipStream_t stream) {
  const float* emission    = (const float*)d_in[0];
  const int*   target      = (const int*)  d_in[1];
  const float* mask        = (const float*)d_in[2];
  const float* start_trans = (const float*)d_in[3];
  const float* trans       = (const float*)d_in[4];
  const float* end_trans   = (const float*)d_in[5];
  float* out = (float*)d_out;

  zero_out_kernel<<<1, 1, 0, stream>>>(out);
  crf_nll_kernel<<<NB / 2, 64, 0, stream>>>(emission, target, mask, start_trans,
                                            trans, end_trans, out);
}

// Round 7
// 204.191 us; speedup vs baseline: 1.9872x; 1.9872x over previous
//
#include <hip/hip_runtime.h>

#define NB 512
#define NT 512
#define NL 64
#define L2E 1.4426950408889634f   // log2(e)
#define LN2 0.6931471805599453f   // ln(2)

typedef _Float16 h2 __attribute__((ext_vector_type(2)));
typedef _Float16 h8 __attribute__((ext_vector_type(8)));

__global__ void zero_out_kernel(float* out) { *out = 0.0f; }

__device__ __forceinline__ float rfl(float x) {
  return __uint_as_float(__builtin_amdgcn_readfirstlane(__float_as_uint(x)));
}

__device__ __forceinline__ float dot2(h2 a, h2 b, float c) {
#if __has_builtin(__builtin_amdgcn_fdot2)
  return __builtin_amdgcn_fdot2(a, b, c, false);
#else
  return fmaf((float)a[0], (float)b[0], fmaf((float)a[1], (float)b[1], c));
#endif
}

// R7: back to R5 shape (512 blocks, 1 batch/wave -- R6 proved in-wave dual
// chains serialize: issue doubles, no latency overlap; co-resident waves do
// the hiding for free). Cut per-step ISSUE cost instead: q broadcast as f16
// (8 ds_read_b128/step, was 16) + v_dot2_f32_f16 (32 instrs, was 64 FMAs).
// f16 safety: rescale EVERY step by lane-0 q (per-step cross-lane spread
// <= ~e^10 < f16 max e^11.08). Still call-free (R5 lesson: OCML calls pin
// live values into spill slots -- VGPR_Count was stuck at 68 until R5).
__global__
__attribute__((amdgpu_flat_work_group_size(64, 64), amdgpu_waves_per_eu(1, 1)))
void crf_nll_kernel(
    const float* __restrict__ emission,     // B,T,L
    const int*   __restrict__ target,       // B,T
    const float* __restrict__ mask,         // B,T
    const float* __restrict__ start_trans,  // L
    const float* __restrict__ trans,        // L,L
    const float* __restrict__ end_trans,    // L
    float* __restrict__ out)
{
  const int b = blockIdx.x;
  const int j = threadIdx.x;  // 0..63

  const float* em_b = emission + (size_t)b * NT * NL;
  const float* mk_b = mask + (size_t)b * NT;
  const int*   tg_b = target + (size_t)b * NT;

  // ---------------- path score (parallel over t, then wave-reduce) ----------
  float ps = 0.0f;
  #pragma unroll
  for (int c = 0; c < NT / 64; ++c) {
    int t = c * 64 + j;
    int cur = tg_b[t];
    float m  = mk_b[t];
    float mn = (t + 1 < NT) ? mk_b[t + 1] : 0.0f;
    if (t == 0) {
      ps += start_trans[cur] + em_b[cur];              // ps0, unconditional
    } else {
      int prev = tg_b[t - 1];
      if (m > 0.5f)
        ps += trans[prev * NL + cur] + em_b[(size_t)t * NL + cur];
      if (m - mn > 0.5f)                               // end_mask = m_t & !m_{t+1}
        ps += end_trans[cur];
    }
  }
  #pragma unroll
  for (int off = 32; off; off >>= 1) ps += __shfl_down(ps, off, 64);
  // lane 0 now holds the batch path score

  // ---- exp2-domain trans column, packed f16 pairs: ep[k]=(E[2k],E[2k+1]) ---
  h2 ep[NL / 2];
  #pragma unroll
  for (int k = 0; k < NL / 2; ++k) {
    float e0 = __builtin_amdgcn_exp2f(L2E * trans[(2 * k + 0) * NL + j]);
    float e1 = __builtin_amdgcn_exp2f(L2E * trans[(2 * k + 1) * NL + j]);
    h2 v; v[0] = (_Float16)e0; v[1] = (_Float16)e1;
    ep[k] = v;
  }
  const float endt = __builtin_amdgcn_exp2f(L2E * end_trans[j]);

  __shared__ __align__(16) _Float16 qh[NL];
  const h8* qv = (const h8*)qh;   // 8 f16 per 16B read; 8 reads cover all 64

  float C = 0.0f;   // accumulated scale, log2 units
  float q = __builtin_amdgcn_exp2f(L2E * (start_trans[j] + em_b[j]));  // t=0
  { // normalize before first f16 write
    float r = rfl(q);
    q *= __builtin_amdgcn_rcpf(r);
    C += __builtin_amdgcn_logf(r);                     // log2
  }

  // 8-deep emission FIFO, pre-scaled by log2(e): pf[t&7] = l2e*em[t][j]
  float pf[8];
  #pragma unroll
  for (int u = 0; u < 8; ++u) pf[u] = L2E * em_b[(size_t)u * NL + j];

  #pragma unroll 1
  for (int c = 0; c < 8; ++c) {
    const int tb = c * 64;
    // per-chunk masks as wave-uniform 64-bit ballot words
    float ml = mk_b[tb + j];
    int nidx = tb + j + 1;
    float mnext = (nidx < NT) ? mk_b[nidx] : 0.0f;
    unsigned long long mbits = __ballot(ml > 0.5f);
    unsigned long long ebits = __ballot(ml - mnext > 0.5f);
    if (c == 0) { mbits &= ~1ull; ebits &= ~1ull; }   // t=0 handled by init

    #pragma unroll 1
    for (int i8 = 0; i8 < 64; i8 += 8) {
      #pragma unroll
      for (int u = 0; u < 8; ++u) {
        const int i = i8 + u;
        float eem = __builtin_amdgcn_exp2f(pf[u]);     // off-chain exp
        int tp = tb + i + 8; if (tp > NT - 1) tp = NT - 1;
        pf[u] = L2E * em_b[(size_t)tp * NL + j];       // prefetch t+8
        qh[j] = (_Float16)q;                           // 128B broadcast state
        float a0 = 0.f, a1 = 0.f, a2 = 0.f, a3 = 0.f;
        #pragma unroll
        for (int k = 0; k < 8; ++k) {
          h8 x = qv[k];                                // ds_read_b128
          h2 x0 = __builtin_shufflevector(x, x, 0, 1);
          h2 x1 = __builtin_shufflevector(x, x, 2, 3);
          h2 x2 = __builtin_shufflevector(x, x, 4, 5);
          h2 x3 = __builtin_shufflevector(x, x, 6, 7);
          a0 = dot2(x0, ep[4 * k + 0], a0);
          a1 = dot2(x1, ep[4 * k + 1], a1);
          a2 = dot2(x2, ep[4 * k + 2], a2);
          a3 = dot2(x3, ep[4 * k + 3], a3);
        }
        float sm = (((a0 + a1) + (a2 + a3))) * eem;
        q = ((mbits >> i) & 1) ? sm : q;
        q = ((ebits >> i) & 1) ? q * endt : q;
        // per-step rescale: keeps f16 write in range (spread < e^11)
        float r = rfl(q);
        q *= __builtin_amdgcn_rcpf(r);
        C += __builtin_amdgcn_logf(r);                 // log2, off-chain
      }
    }
  }

  // ---------------- normalizer + output -------------------------------------
  float s = q;
  #pragma unroll
  for (int off = 32; off; off >>= 1) s += __shfl_xor(s, off, 64);
  if (j == 0) {
    float norm = (__builtin_amdgcn_logf(s) + C) * LN2;  // back to natural log
    atomicAdd(out, (norm - ps) * (1.0f / (float)NB));
  }
}

extern "C" void kernel_launch(void* const* d_in, const int* in_sizes, int n_in,
                              void* d_out, int out_size, void* d_ws, size_t ws_size,
                              hipStream_t stream) {
  const float* emission    = (const float*)d_in[0];
  const int*   target      = (const int*)  d_in[1];
  const float* mask        = (const float*)d_in[2];
  const float* start_trans = (const float*)d_in[3];
  const float* trans       = (const float*)d_in[4];
  const float* end_trans   = (const float*)d_in[5];
  float* out = (float*)d_out;

  zero_out_kernel<<<1, 1, 0, stream>>>(out);
  crf_nll_kernel<<<NB, 64, 0, stream>>>(emission, target, mask, start_trans,
                                        trans, end_trans, out);
}

// Round 8
// 201.744 us; speedup vs baseline: 2.0113x; 1.0121x over previous
//
#include <hip/hip_runtime.h>

#define NB 512
#define NT 512
#define NL 64
#define L2E 1.4426950408889634f   // log2(e)
#define LN2 0.6931471805599453f   // ln(2)

typedef _Float16 h2 __attribute__((ext_vector_type(2)));
typedef _Float16 h8 __attribute__((ext_vector_type(8)));

__global__ void zero_out_kernel(float* out) { *out = 0.0f; }

__device__ __forceinline__ float dot2(h2 a, h2 b, float c) {
#if __has_builtin(__builtin_amdgcn_fdot2)
  return __builtin_amdgcn_fdot2(a, b, c, false);
#else
  return fmaf((float)a[0], (float)b[0], fmaf((float)a[1], (float)b[1], c));
#endif
}

// R8: chain surgery on R7. Per-step critical chain is now only
//   write -> 8x ds_read_b128 -> dot tree (8 acc) -> exponent-rescale (exact
//   2^c via bit-built multiplier) -> mul eem_eff -> cndmask -> cvt -> write.
// All else (exp2, endt fold, prefetch, G accumulation) sits in the ~210-cyc
// LDS-wait shadow. Rescale is keyed to lane-0 EXPONENT of the pre-em sum sm,
// so the f16 write range is bounded ~2^±8 regardless of tails; the scale
// accumulator G is an exact integer (no v_rcp / v_log on chain, no rounding).
// Lessons kept: no OCML calls (R5), 1 batch/wave TLP (R6), f16+dot2 (R7).
__global__
__attribute__((amdgpu_flat_work_group_size(64, 64), amdgpu_waves_per_eu(1, 1)))
void crf_nll_kernel(
    const float* __restrict__ emission,     // B,T,L
    const int*   __restrict__ target,       // B,T
    const float* __restrict__ mask,         // B,T
    const float* __restrict__ start_trans,  // L
    const float* __restrict__ trans,        // L,L
    const float* __restrict__ end_trans,    // L
    float* __restrict__ out)
{
  const int b = blockIdx.x;
  const int j = threadIdx.x;  // 0..63

  const float* em_b = emission + (size_t)b * NT * NL;
  const float* mk_b = mask + (size_t)b * NT;
  const int*   tg_b = target + (size_t)b * NT;

  // ---------------- path score (parallel over t, then wave-reduce) ----------
  float ps = 0.0f;
  #pragma unroll
  for (int c = 0; c < NT / 64; ++c) {
    int t = c * 64 + j;
    int cur = tg_b[t];
    float m  = mk_b[t];
    float mn = (t + 1 < NT) ? mk_b[t + 1] : 0.0f;
    if (t == 0) {
      ps += start_trans[cur] + em_b[cur];              // ps0, unconditional
    } else {
      int prev = tg_b[t - 1];
      if (m > 0.5f)
        ps += trans[prev * NL + cur] + em_b[(size_t)t * NL + cur];
      if (m - mn > 0.5f)                               // end_mask = m_t & !m_{t+1}
        ps += end_trans[cur];
    }
  }
  #pragma unroll
  for (int off = 32; off; off >>= 1) ps += __shfl_down(ps, off, 64);
  // lane 0 now holds the batch path score

  // ---- exp2-domain trans column, packed f16 pairs: ep[k]=(E[2k],E[2k+1]) ---
  h2 ep[NL / 2];
  #pragma unroll
  for (int k = 0; k < NL / 2; ++k) {
    float e0 = __builtin_amdgcn_exp2f(L2E * trans[(2 * k + 0) * NL + j]);
    float e1 = __builtin_amdgcn_exp2f(L2E * trans[(2 * k + 1) * NL + j]);
    h2 v; v[0] = (_Float16)e0; v[1] = (_Float16)e1;
    ep[k] = v;
  }
  const float endt = __builtin_amdgcn_exp2f(L2E * end_trans[j]);

  __shared__ __align__(16) _Float16 qh[NL];
  const h8* qv = (const h8*)qh;   // 8 f16 per 16B read; 8 reads cover all 64

  int G = 0;        // exact integer scale accumulator (log2 units)
  float s = __builtin_amdgcn_exp2f(L2E * (start_trans[j] + em_b[j]));  // t=0
  qh[j] = (_Float16)s;                                 // boot write (2^±7 ok)

  // 8-deep emission FIFO, pre-scaled by log2(e): pf[t&7] = l2e*em[t][j]
  float pf[8];
  #pragma unroll
  for (int u = 0; u < 8; ++u) pf[u] = L2E * em_b[(size_t)u * NL + j];

  #pragma unroll 1
  for (int c = 0; c < 8; ++c) {
    const int tb = c * 64;
    // per-chunk masks as wave-uniform 64-bit ballot words
    float ml = mk_b[tb + j];
    int nidx = tb + j + 1;
    float mnext = (nidx < NT) ? mk_b[nidx] : 0.0f;
    unsigned long long mbits = __ballot(ml > 0.5f);
    unsigned long long ebits = __ballot(ml - mnext > 0.5f);
    if (c == 0) { mbits &= ~1ull; ebits &= ~1ull; }   // t=0 handled by init

    #pragma unroll 1
    for (int i8 = 0; i8 < 64; i8 += 8) {
      #pragma unroll
      for (int u = 0; u < 8; ++u) {
        const int i = i8 + u;
        // ---- off-chain: eem_eff (endt folded), prefetch t+8 --------------
        float eemu = __builtin_amdgcn_exp2f(pf[u]);
        eemu = ((ebits >> i) & 1) ? eemu * endt : eemu;
        int tp = tb + i + 8; if (tp > NT - 1) tp = NT - 1;
        pf[u] = L2E * em_b[(size_t)tp * NL + j];
        // ---- chain: 8 reads -> 8-acc dot -> exp-rescale -> select --------
        float a0 = 0.f, a1 = 0.f, a2 = 0.f, a3 = 0.f;
        float a4 = 0.f, a5 = 0.f, a6 = 0.f, a7 = 0.f;
        #pragma unroll
        for (int k = 0; k < 8; ++k) {
          h8 x = qv[k];                                // ds_read_b128
          h2 x0 = __builtin_shufflevector(x, x, 0, 1);
          h2 x1 = __builtin_shufflevector(x, x, 2, 3);
          h2 x2 = __builtin_shufflevector(x, x, 4, 5);
          h2 x3 = __builtin_shufflevector(x, x, 6, 7);
          if (k & 1) {
            a4 = dot2(x0, ep[4 * k + 0], a4);
            a5 = dot2(x1, ep[4 * k + 1], a5);
            a6 = dot2(x2, ep[4 * k + 2], a6);
            a7 = dot2(x3, ep[4 * k + 3], a7);
          } else {
            a0 = dot2(x0, ep[4 * k + 0], a0);
            a1 = dot2(x1, ep[4 * k + 1], a1);
            a2 = dot2(x2, ep[4 * k + 2], a2);
            a3 = dot2(x3, ep[4 * k + 3], a3);
          }
        }
        float sm = (((a0 + a4) + (a1 + a5)) + ((a2 + a6) + (a3 + a7)));
        // lane-0 exponent of sm -> exact scale 2^(127-e0)
        unsigned e0 =
            (__builtin_amdgcn_readfirstlane(__float_as_uint(sm)) >> 23) & 0xffu;
        float scale = __uint_as_float((254u - e0) << 23);  // 2^(127-e0), exact
        float snew = (sm * scale) * eemu;
        float sold = s * scale;                        // old path, same scale
        s = ((mbits >> i) & 1) ? snew : sold;
        qh[j] = (_Float16)s;                           // range ~2^±8: f16 safe
        G += (int)e0 - 127;                            // exact, off-chain
      }
    }
  }

  // ---------------- normalizer + output -------------------------------------
  float ssum = s;
  #pragma unroll
  for (int off = 32; off; off >>= 1) ssum += __shfl_xor(ssum, off, 64);
  if (j == 0) {
    float norm = (__builtin_amdgcn_logf(ssum) + (float)G) * LN2;  // nat log
    atomicAdd(out, (norm - ps) * (1.0f / (float)NB));
  }
}

extern "C" void kernel_launch(void* const* d_in, const int* in_sizes, int n_in,
                              void* d_out, int out_size, void* d_ws, size_t ws_size,
                              hipStream_t stream) {
  const float* emission    = (const float*)d_in[0];
  const int*   target      = (const int*)  d_in[1];
  const float* mask        = (const float*)d_in[2];
  const float* start_trans = (const float*)d_in[3];
  const float* trans       = (const float*)d_in[4];
  const float* end_trans   = (const float*)d_in[5];
  float* out = (float*)d_out;

  zero_out_kernel<<<1, 1, 0, stream>>>(out);
  crf_nll_kernel<<<NB, 64, 0, stream>>>(emission, target, mask, start_trans,
                                        trans, end_trans, out);
}